// Round 13
// baseline (64.406 us; speedup 1.0000x reference)
//
#include <hip/hip_runtime.h>

#define B_ 4
#define C_ 64
#define H_ 128
#define W_ 128
#define LOG2E 1.44269504088896340736f

typedef float v2f __attribute__((ext_vector_type(2)));

__device__ __forceinline__ v2f exp2v(v2f x) {
    return (v2f){ __builtin_amdgcn_exp2f(x.x), __builtin_amdgcn_exp2f(x.y) };
}

// DIAGNOSTIC build of the best (R7) kernel: identical structure, whole body
// repeated 4x behind an opaque asm barrier so the dispatch exceeds the
// harness's ~40us fill kernels and shows up in rocprof top-5 with real
// counters (VALUBusy / Occupancy / VGPR). Stores are idempotent -> correct.
template<int HALF>
__device__ __forceinline__ void sa_body(int x0, int y0,
    const float* __restrict__ f1p, const float* __restrict__ f2p,
    const float* __restrict__ relp, float* __restrict__ outp)
{
    float rel5[5];
    #pragma unroll
    for (int k = 0; k < 5; ++k) rel5[k] = relp[k];

    const float mL = (x0 > 0) ? 1.0f : 0.0f;
    const float mR = (x0 < W_ - 4) ? 1.0f : 0.0f;
    const int eM = (x0 >= 4) ? x0 - 4 : 0;
    const int eP = (x0 <= W_ - 8) ? x0 + 4 : W_ - 4;

    float w[5][8];   // rolling window: image row (y0 + s - 2) in slot s (mod 5)

    auto load_row = [&](int slot, int ky) {
        const int kycl = ky < 0 ? 0 : (ky > H_ - 1 ? H_ - 1 : ky);
        const float rv = ((unsigned)ky < (unsigned)H_) ? 1.0f : 0.0f;
        const float* rp = f2p + kycl * W_;
        const float4 qm = *(const float4*)(rp + eM);
        const float4 q0 = *(const float4*)(rp + x0);
        const float4 qp = *(const float4*)(rp + eP);
        const float mLr = mL * rv, mRr = mR * rv;
        w[slot][0] = qm.z * mLr; w[slot][1] = qm.w * mLr;
        w[slot][2] = q0.x * rv;  w[slot][3] = q0.y * rv;
        w[slot][4] = q0.z * rv;  w[slot][5] = q0.w * rv;
        w[slot][6] = qp.x * mRr; w[slot][7] = qp.y * mRr;
    };

    #pragma unroll
    for (int t = 0; t < 4; ++t) load_row(t, y0 + t - 2);

    #pragma unroll
    for (int r = 0; r < 4; ++r) {
        load_row((r + 4) % 5, y0 + r + 2);

        const float4 q4 = *(const float4*)(f1p + (y0 + r) * W_ + x0);
        const float qs[4] = {q4.x, q4.y, q4.z, q4.w};
        float res[4];

        #pragma unroll
        for (int xo = 0; xo < 4; ++xo) {
            const float q2 = qs[xo] * LOG2E;
            const v2f q2v = {q2, q2};

            float pr[5];
            #pragma unroll
            for (int k = 0; k < 5; ++k) pr[k] = q2 * rel5[k];
            const v2f prA = {pr[0], pr[1]};
            const v2f prB = {pr[2], pr[3]};
            const float prC = pr[4];

            v2f s0 = {0.f, 0.f}, s1 = {0.f, 0.f};
            v2f d0 = {0.f, 0.f}, d1 = {0.f, 0.f};
            float lv[5];

            #pragma unroll
            for (int i = 0; i < 5; ++i) {
                const float* W8 = w[(r + i) % 5];
                const v2f va = {W8[xo + 0], W8[xo + 1]};
                const v2f vb = {W8[xo + 2], W8[xo + 3]};
                const v2f pa = (HALF == 0) ? (v2f){pr[i], pr[i]} : prA;
                const v2f pb = (HALF == 0) ? (v2f){pr[i], pr[i]} : prB;
                const v2f p0 = exp2v(__builtin_elementwise_fma(va, q2v, pa));
                s0 += p0; d0 = __builtin_elementwise_fma(p0, va, d0);
                const v2f p1 = exp2v(__builtin_elementwise_fma(vb, q2v, pb));
                s1 += p1; d1 = __builtin_elementwise_fma(p1, vb, d1);
                lv[i] = W8[xo + 4];
            }
            {
                const v2f v = {lv[0], lv[1]};
                const v2f pp = (HALF == 0) ? (v2f){pr[0], pr[1]} : (v2f){prC, prC};
                const v2f p = exp2v(__builtin_elementwise_fma(v, q2v, pp));
                s0 += p; d0 = __builtin_elementwise_fma(p, v, d0);
            }
            {
                const v2f v = {lv[2], lv[3]};
                const v2f pp = (HALF == 0) ? (v2f){pr[2], pr[3]} : (v2f){prC, prC};
                const v2f p = exp2v(__builtin_elementwise_fma(v, q2v, pp));
                s1 += p; d1 = __builtin_elementwise_fma(p, v, d1);
            }
            float ss, ds;
            {
                const float pp = (HALF == 0) ? pr[4] : prC;
                const float p = __builtin_amdgcn_exp2f(__builtin_fmaf(q2, lv[4], pp));
                ss = p; ds = p * lv[4];
            }
            const v2f st = s0 + s1, dt = d0 + d1;
            res[xo] = (dt.x + dt.y + ds) * __builtin_amdgcn_rcpf(st.x + st.y + ss);
        }

        *(float4*)(outp + (y0 + r) * W_ + x0) = (float4){res[0], res[1], res[2], res[3]};
    }
}

__global__ __launch_bounds__(256) void sa_kernel(
    const float* __restrict__ f1, const float* __restrict__ f2,
    const float* __restrict__ relh, const float* __restrict__ relw,
    float* __restrict__ out)
{
    const int tid   = threadIdx.x;
    const int xq    = tid & 31;
    const int ys    = tid >> 5;
    const int blk   = blockIdx.x;
    const int chunk = blk & 3;
    const int bc    = blk >> 2;
    const int c     = bc & (C_ - 1);
    const int b     = bc >> 6;
    const int x0    = xq << 2;
    const int y0    = chunk * 32 + ys * 4;

    const size_t img = (size_t)(b * C_ + c) * (H_ * W_);
    const float* f1p = f1 + img;
    const float* f2p = f2 + img;

    const int c_out = (c & 7) * 8 + (c >> 3);
    float* outp = out + (size_t)(b * C_ + c_out) * (H_ * W_);

    const float* relp = (c < C_ / 2) ? (relh + c * 5) : (relw + (c - C_ / 2) * 5);

    // Opaque x4 repeat: pointers re-materialized and memory re-read each
    // iteration (asm barrier), so the full load+compute+store pipeline runs
    // 4 times. Output values are identical each pass -> still correct.
    for (int it = 0; it < 4; ++it) {
        asm volatile("" : "+v"(f1p), "+v"(f2p), "+v"(outp), "+v"(relp) :: "memory");
        if (c < C_ / 2) sa_body<0>(x0, y0, f1p, f2p, relp, outp);
        else            sa_body<1>(x0, y0, f1p, f2p, relp, outp);
    }
}

extern "C" void kernel_launch(void* const* d_in, const int* in_sizes, int n_in,
                              void* d_out, int out_size, void* d_ws, size_t ws_size,
                              hipStream_t stream) {
    const float* f1   = (const float*)d_in[0];
    const float* f2   = (const float*)d_in[1];
    const float* relh = (const float*)d_in[2];
    const float* relw = (const float*)d_in[3];
    float* out = (float*)d_out;

    const int grid = B_ * C_ * 4;   // 1024 blocks, 4/CU (same as R7)
    sa_kernel<<<grid, 256, 0, stream>>>(f1, f2, relh, relw, out);
}

// Round 14
// 24.437 us; speedup vs baseline: 2.6355x; 2.6355x over previous
//
#include <hip/hip_runtime.h>

#define B_ 4
#define C_ 64
#define H_ 128
#define W_ 128
#define LOG2E 1.44269504088896340736f

// Scalar-clean build: NO packed v2f math (VOP3P f32 needs even-aligned reg
// pairs; odd-offset pair builds cost 2 v_movs per op and bloat the stream).
// Thread: 4 consecutive x (aligned quad) x 2 consecutive y; w[6][8] window
// from 3 aligned float4 loads/row; pure fmaf/exp2/add inner loop.
template<int HALF>
__device__ __forceinline__ void sa_body(int x0, int y0,
    const float* __restrict__ f1p, const float* __restrict__ f2p,
    const float* __restrict__ relp, float* __restrict__ outp)
{
    float rel5[5];
    #pragma unroll
    for (int k = 0; k < 5; ++k) rel5[k] = relp[k];

    const float mL = (x0 > 0) ? 1.0f : 0.0f;
    const float mR = (x0 < W_ - 4) ? 1.0f : 0.0f;
    const int eM = (x0 >= 4) ? x0 - 4 : 0;
    const int eP = (x0 <= W_ - 8) ? x0 + 4 : W_ - 4;

    // window rows y0-2 .. y0+3, cols x0-2 .. x0+5
    float w[6][8];
    #pragma unroll
    for (int t = 0; t < 6; ++t) {
        const int ky = y0 + t - 2;
        const int kycl = ky < 0 ? 0 : (ky > H_ - 1 ? H_ - 1 : ky);
        const float rv = ((unsigned)ky < (unsigned)H_) ? 1.0f : 0.0f;
        const float* rp = f2p + kycl * W_;
        const float4 qm = *(const float4*)(rp + eM);
        const float4 q0 = *(const float4*)(rp + x0);
        const float4 qp = *(const float4*)(rp + eP);
        const float mLr = mL * rv, mRr = mR * rv;
        w[t][0] = qm.z * mLr; w[t][1] = qm.w * mLr;
        w[t][2] = q0.x * rv;  w[t][3] = q0.y * rv;
        w[t][4] = q0.z * rv;  w[t][5] = q0.w * rv;
        w[t][6] = qp.x * mRr; w[t][7] = qp.y * mRr;
    }

    #pragma unroll
    for (int r = 0; r < 2; ++r) {
        const float4 q4 = *(const float4*)(f1p + (y0 + r) * W_ + x0);
        const float qarr[4] = {q4.x, q4.y, q4.z, q4.w};
        float res[4];

        #pragma unroll
        for (int xo = 0; xo < 4; ++xo) {
            const float q2 = qarr[xo] * LOG2E;
            float pr[5];
            #pragma unroll
            for (int k = 0; k < 5; ++k) pr[k] = q2 * rel5[k];

            // no max-subtraction: |q2*(v+rel)| < ~80 << 128, exp2 can't overflow
            float s0 = 0.f, s1 = 0.f, d0 = 0.f, d1 = 0.f;
            #pragma unroll
            for (int i = 0; i < 5; ++i) {
                const float* row = w[r + i];
                #pragma unroll
                for (int j = 0; j < 5; ++j) {
                    const float v = row[xo + j];
                    const float p = __builtin_amdgcn_exp2f(
                        __builtin_fmaf(q2, v, pr[HALF ? j : i]));
                    if ((j & 1) == 0) { s0 += p; d0 = __builtin_fmaf(p, v, d0); }
                    else              { s1 += p; d1 = __builtin_fmaf(p, v, d1); }
                }
            }
            res[xo] = (d0 + d1) * __builtin_amdgcn_rcpf(s0 + s1);
        }

        *(float4*)(outp + (y0 + r) * W_ + x0) = (float4){res[0], res[1], res[2], res[3]};
    }
}

__global__ __launch_bounds__(256) void sa_kernel(
    const float* __restrict__ f1, const float* __restrict__ f2,
    const float* __restrict__ relh, const float* __restrict__ relw,
    float* __restrict__ out)
{
    const int tid = threadIdx.x;
    const int xq  = tid & 31;            // 32 x-quads = full width
    const int ys  = tid >> 5;            // 8 y-strips of 2 rows -> 16 rows per block
    const int blk = blockIdx.x;
    const int yb  = blk & 7;             // 8 blocks per image
    const int bc  = blk >> 3;
    const int c   = bc & (C_ - 1);
    const int b   = bc >> 6;
    const int x0  = xq << 2;
    const int y0  = yb * 16 + ys * 2;

    const size_t img = (size_t)(b * C_ + c) * (H_ * W_);
    const float* f1p = f1 + img;
    const float* f2p = f2 + img;

    const int c_out = (c & 7) * 8 + (c >> 3);   // einsum channel transpose
    float* outp = out + (size_t)(b * C_ + c_out) * (H_ * W_);

    if (c < C_ / 2) sa_body<0>(x0, y0, f1p, f2p, relh + c * 5, outp);
    else            sa_body<1>(x0, y0, f1p, f2p, relw + (c - C_ / 2) * 5, outp);
}

extern "C" void kernel_launch(void* const* d_in, const int* in_sizes, int n_in,
                              void* d_out, int out_size, void* d_ws, size_t ws_size,
                              hipStream_t stream) {
    const float* f1   = (const float*)d_in[0];
    const float* f2   = (const float*)d_in[1];
    const float* relh = (const float*)d_in[2];
    const float* relw = (const float*)d_in[3];
    float* out = (float*)d_out;

    const int grid = B_ * C_ * 8;   // 2048 blocks
    sa_kernel<<<grid, 256, 0, stream>>>(f1, f2, relh, relw, out);
}

// Round 15
// 24.076 us; speedup vs baseline: 2.6751x; 1.0150x over previous
//
#include <hip/hip_runtime.h>

#define B_ 4
#define C_ 64
#define H_ 128
#define W_ 128
#define LOG2E 1.44269504088896340736f

typedef float v2f __attribute__((ext_vector_type(2)));

// Thread: 4 consecutive x (aligned quad) x 2 SEPARATED rows (y and y+8).
// Every VOP3P operand pair is {stripA, stripB} — built by the mandatory
// border-mask muls writing into pair halves, so no mov repacking and no
// sliding-window misalignment. 25 exps/output remain on the trans pipe.
// HALF=0: rel indexed by window row i; HALF=1: by window col j.
template<int HALF>
__device__ __forceinline__ void sa_body(int x0, int yA, int yB,
    const float* __restrict__ f1p, const float* __restrict__ f2p,
    const float* __restrict__ relp, float* __restrict__ outp)
{
    float rel5[5];                       // block-uniform -> scalar regs
    #pragma unroll
    for (int k = 0; k < 5; ++k) rel5[k] = relp[k];

    const float mL = (x0 > 0) ? 1.0f : 0.0f;
    const float mR = (x0 < W_ - 4) ? 1.0f : 0.0f;
    const int eM = (x0 >= 4) ? x0 - 4 : 0;
    const int eP = (x0 <= W_ - 8) ? x0 + 4 : W_ - 4;

    // paired window: wp[t][c] = { stripA row (yA+t-2) col (x0+c-2),
    //                             stripB row (yB+t-2) col (x0+c-2) }
    v2f wp[5][8];
    #pragma unroll
    for (int t = 0; t < 5; ++t) {
        {   // strip A half
            const int ky = yA + t - 2;
            const int kycl = ky < 0 ? 0 : (ky > H_ - 1 ? H_ - 1 : ky);
            const float rv = ((unsigned)ky < (unsigned)H_) ? 1.0f : 0.0f;
            const float* rp = f2p + kycl * W_;
            const float4 qm = *(const float4*)(rp + eM);
            const float4 q0 = *(const float4*)(rp + x0);
            const float4 qp = *(const float4*)(rp + eP);
            const float mLr = mL * rv, mRr = mR * rv;
            wp[t][0].x = qm.z * mLr; wp[t][1].x = qm.w * mLr;
            wp[t][2].x = q0.x * rv;  wp[t][3].x = q0.y * rv;
            wp[t][4].x = q0.z * rv;  wp[t][5].x = q0.w * rv;
            wp[t][6].x = qp.x * mRr; wp[t][7].x = qp.y * mRr;
        }
        {   // strip B half
            const int ky = yB + t - 2;
            const int kycl = ky < 0 ? 0 : (ky > H_ - 1 ? H_ - 1 : ky);
            const float rv = ((unsigned)ky < (unsigned)H_) ? 1.0f : 0.0f;
            const float* rp = f2p + kycl * W_;
            const float4 qm = *(const float4*)(rp + eM);
            const float4 q0 = *(const float4*)(rp + x0);
            const float4 qp = *(const float4*)(rp + eP);
            const float mLr = mL * rv, mRr = mR * rv;
            wp[t][0].y = qm.z * mLr; wp[t][1].y = qm.w * mLr;
            wp[t][2].y = q0.x * rv;  wp[t][3].y = q0.y * rv;
            wp[t][4].y = q0.z * rv;  wp[t][5].y = q0.w * rv;
            wp[t][6].y = qp.x * mRr; wp[t][7].y = qp.y * mRr;
        }
    }

    const float4 qA4 = *(const float4*)(f1p + yA * W_ + x0);
    const float4 qB4 = *(const float4*)(f1p + yB * W_ + x0);
    const float qAa[4] = {qA4.x, qA4.y, qA4.z, qA4.w};
    const float qBa[4] = {qB4.x, qB4.y, qB4.z, qB4.w};
    float resA[4], resB[4];

    #pragma unroll
    for (int xo = 0; xo < 4; ++xo) {
        const v2f q2 = { qAa[xo] * LOG2E, qBa[xo] * LOG2E };

        v2f pr[5];                       // {q2A*rel_k, q2B*rel_k}
        #pragma unroll
        for (int k = 0; k < 5; ++k) pr[k] = q2 * rel5[k];

        // no max-subtraction: |q2*(v+rel)| < ~80 << 128, exp2 can't overflow
        v2f s0 = {0.f,0.f}, s1 = {0.f,0.f}, d0 = {0.f,0.f}, d1 = {0.f,0.f};
        #pragma unroll
        for (int i = 0; i < 5; ++i) {
            #pragma unroll
            for (int j = 0; j < 5; ++j) {
                const v2f v  = wp[i][xo + j];
                const v2f sc = __builtin_elementwise_fma(v, q2, pr[HALF ? j : i]);
                const v2f p  = { __builtin_amdgcn_exp2f(sc.x),
                                 __builtin_amdgcn_exp2f(sc.y) };
                if (((i * 5 + j) & 1) == 0) { s0 += p; d0 = __builtin_elementwise_fma(p, v, d0); }
                else                        { s1 += p; d1 = __builtin_elementwise_fma(p, v, d1); }
            }
        }
        const v2f st = s0 + s1, dt = d0 + d1;
        resA[xo] = dt.x * __builtin_amdgcn_rcpf(st.x);
        resB[xo] = dt.y * __builtin_amdgcn_rcpf(st.y);
    }

    *(float4*)(outp + yA * W_ + x0) = (float4){resA[0], resA[1], resA[2], resA[3]};
    *(float4*)(outp + yB * W_ + x0) = (float4){resB[0], resB[1], resB[2], resB[3]};
}

__global__ __launch_bounds__(256) void sa_kernel(
    const float* __restrict__ f1, const float* __restrict__ f2,
    const float* __restrict__ relh, const float* __restrict__ relw,
    float* __restrict__ out)
{
    const int tid = threadIdx.x;
    const int xq  = tid & 31;            // 32 x-quads = full width
    const int ys  = tid >> 5;            // 0..7
    const int blk = blockIdx.x;
    const int yb  = blk & 7;             // 8 blocks per image (16 rows each)
    const int bc  = blk >> 3;
    const int c   = bc & (C_ - 1);
    const int b   = bc >> 6;
    const int x0  = xq << 2;
    const int yA  = yb * 16 + ys;        // strip A row
    const int yB  = yA + 8;              // strip B row (disjoint window)

    const size_t img = (size_t)(b * C_ + c) * (H_ * W_);
    const float* f1p = f1 + img;
    const float* f2p = f2 + img;

    const int c_out = (c & 7) * 8 + (c >> 3);   // einsum channel transpose
    float* outp = out + (size_t)(b * C_ + c_out) * (H_ * W_);

    if (c < C_ / 2) sa_body<0>(x0, yA, yB, f1p, f2p, relh + c * 5, outp);
    else            sa_body<1>(x0, yA, yB, f1p, f2p, relw + (c - C_ / 2) * 5, outp);
}

extern "C" void kernel_launch(void* const* d_in, const int* in_sizes, int n_in,
                              void* d_out, int out_size, void* d_ws, size_t ws_size,
                              hipStream_t stream) {
    const float* f1   = (const float*)d_in[0];
    const float* f2   = (const float*)d_in[1];
    const float* relh = (const float*)d_in[2];
    const float* relw = (const float*)d_in[3];
    float* out = (float*)d_out;

    const int grid = B_ * C_ * 8;   // 2048 blocks
    sa_kernel<<<grid, 256, 0, stream>>>(f1, f2, relh, relw, out);
}